// Round 2
// baseline (503.057 us; speedup 1.0000x reference)
//
#include <hip/hip_runtime.h>
#include <hip/hip_bf16.h>

using f32x4  = __attribute__((ext_vector_type(4))) float;
using bf16x8 = __attribute__((ext_vector_type(8))) short;
using bf16x4 = __attribute__((ext_vector_type(4))) short;
using u32x2  = __attribute__((ext_vector_type(2))) unsigned int;
using u32x4  = __attribute__((ext_vector_type(4))) unsigned int;

__device__ __forceinline__ float bf2f(short s) {
    unsigned u = ((unsigned)(unsigned short)s) << 16;
    return __builtin_bit_cast(float, u);
}
__device__ __forceinline__ unsigned short f2b(float f) {
    unsigned u = __builtin_bit_cast(unsigned, f);
    unsigned r = u + 0x7FFFu + ((u >> 16) & 1u);   // RNE
    return (unsigned short)(r >> 16);
}

// window-local row -> global x row (row in [0,126) within a 14-window block)
__device__ __forceinline__ int grow_of(int wbase, int row) {
    int wi = row / 9;
    int t  = row - wi * 9;
    int w  = wbase + wi;
    if (w >= 16384) return -1;
    int b = w >> 10, rem = w & 1023;
    int wh = rem >> 5, ww = rem & 31;
    int r = t / 3, c = t - r * 3;
    return b * 9216 + (wh * 3 + r) * 96 + ww * 3 + c;
}

// ---------------- weight convert: Wqkv (768x256) + Wproj (256x256) -> bf16 ----------------
__global__ void k_wconv(const float* __restrict__ wq, const float* __restrict__ wp,
                        unsigned short* __restrict__ out) {
    int i = blockIdx.x * 256 + threadIdx.x;       // grid covers exactly 262144
    float v = (i < 196608) ? wq[i] : wp[i - 196608];
    out[i] = f2b(v);
}

// ---------------- fused window-gather + qkv GEMM + attention ----------------
// block: 14 windows (126 rows), 256 threads (4 waves), A in registers, W from L2.
// LDS: only current head's q,k,v (53.4 KB) -> 3 blocks/CU.
__global__ __launch_bounds__(256, 3) void k_winattn(
    const float* __restrict__ x,
    const unsigned short* __restrict__ wqkv,   // bf16 [768][256]  ([N][K])
    unsigned short* __restrict__ aout)         // bf16 [147456][256], x-row order
{
    constexpr int LQ0 = 68, LQ12 = 72;
    __shared__ unsigned short Qb0[126 * LQ0];      // q of current head
    __shared__ unsigned short Qb1[126 * LQ12];     // k
    __shared__ unsigned short Qb2[126 * LQ12];     // v

    const int tid = threadIdx.x;
    const int wbase = blockIdx.x * 14;
    const int wv = tid >> 6, ln = tid & 63;
    const int lr = ln & 15, lk = ln >> 4;

    // ---- load A (x rows of this wave) into registers as bf16 fragments ----
    bf16x8 af[2][8];
#pragma unroll
    for (int mi = 0; mi < 2; ++mi) {
        int row = wv * 32 + mi * 16 + lr;
        int gr = (row < 126) ? grow_of(wbase, row) : -1;
        if (gr >= 0) {
            const float* xp = x + (size_t)gr * 256;
#pragma unroll
            for (int kk = 0; kk < 8; ++kk) {
                const f32x4* p = (const f32x4*)(xp + kk * 32 + lk * 8);
                f32x4 f0 = p[0], f1 = p[1];
                bf16x8 v;
#pragma unroll
                for (int j = 0; j < 4; ++j) {
                    v[j]     = (short)f2b(f0[j]);
                    v[4 + j] = (short)f2b(f1[j]);
                }
                af[mi][kk] = v;
            }
        } else {
#pragma unroll
            for (int kk = 0; kk < 8; ++kk) {
                bf16x8 z;
#pragma unroll
                for (int j = 0; j < 8; ++j) z[j] = 0;
                af[mi][kk] = z;
            }
        }
    }

    for (int h = 0; h < 4; ++h) {
        // ---- qkv GEMM for head h: 3 parts x 64 cols, B direct from L2 ----
#pragma unroll
        for (int part = 0; part < 3; ++part) {
            const int j0 = part * 256 + h * 64;
            f32x4 acc[2][4];
#pragma unroll
            for (int mi = 0; mi < 2; ++mi)
#pragma unroll
                for (int ni = 0; ni < 4; ++ni) {
                    f32x4 z = {0.f, 0.f, 0.f, 0.f};
                    acc[mi][ni] = z;
                }
#pragma unroll
            for (int kk = 0; kk < 8; ++kk) {
                bf16x8 w[4];
#pragma unroll
                for (int ni = 0; ni < 4; ++ni)
                    w[ni] = *(const bf16x8*)(wqkv + (size_t)(j0 + ni * 16 + lr) * 256 + kk * 32 + lk * 8);
#pragma unroll
                for (int ni = 0; ni < 4; ++ni) {
                    // swapped operands: lane holds C[m=mi*16+lr][n=ni*16+4*lk+r]
                    acc[0][ni] = __builtin_amdgcn_mfma_f32_16x16x32_bf16(w[ni], af[0][kk], acc[0][ni], 0, 0, 0);
                    acc[1][ni] = __builtin_amdgcn_mfma_f32_16x16x32_bf16(w[ni], af[1][kk], acc[1][ni], 0, 0, 0);
                }
            }
            unsigned short* qp = (part == 0) ? Qb0 : (part == 1 ? Qb1 : Qb2);
            const int LQ = (part == 0) ? LQ0 : LQ12;
#pragma unroll
            for (int mi = 0; mi < 2; ++mi) {
                int row = wv * 32 + mi * 16 + lr;
                if (row < 126) {
#pragma unroll
                    for (int ni = 0; ni < 4; ++ni) {
                        u32x2 u;
                        u[0] = (unsigned)f2b(acc[mi][ni][0]) | ((unsigned)f2b(acc[mi][ni][1]) << 16);
                        u[1] = (unsigned)f2b(acc[mi][ni][2]) | ((unsigned)f2b(acc[mi][ni][3]) << 16);
                        *(u32x2*)&qp[row * LQ + ni * 16 + lk * 4] = u;
                    }
                }
            }
        }
        __syncthreads();

        // ---- attention, head h: thread = (row, d-half), no LDS scratch ----
        {
            const int row = tid >> 1, dh = tid & 1;
            if (row < 126) {
                const int w9 = (row / 9) * 9;
                float qv[32];
#pragma unroll
                for (int g = 0; g < 8; ++g) {
                    bf16x4 v = *(const bf16x4*)&Qb0[row * LQ0 + dh * 32 + g * 4];
#pragma unroll
                    for (int j = 0; j < 4; ++j) qv[g * 4 + j] = bf2f(v[j]);
                }
                float s[9];
#pragma unroll
                for (int kk = 0; kk < 9; ++kk) {
                    float t = 0.f;
#pragma unroll
                    for (int g = 0; g < 4; ++g) {
                        bf16x8 v = *(const bf16x8*)&Qb1[(w9 + kk) * LQ12 + dh * 32 + g * 8];
#pragma unroll
                        for (int j = 0; j < 8; ++j) t += qv[g * 8 + j] * bf2f(v[j]);
                    }
                    s[kk] = t;
                }
#pragma unroll
                for (int kk = 0; kk < 9; ++kk)
                    s[kk] = (s[kk] + __shfl_xor(s[kk], 1)) * 0.125f;
                float m = s[0];
#pragma unroll
                for (int kk = 1; kk < 9; ++kk) m = fmaxf(m, s[kk]);
                float sum = 0.f;
#pragma unroll
                for (int kk = 0; kk < 9; ++kk) { s[kk] = __expf(s[kk] - m); sum += s[kk]; }
                float inv = 1.f / sum;
                float o[32];
#pragma unroll
                for (int d = 0; d < 32; ++d) o[d] = 0.f;
#pragma unroll
                for (int kk = 0; kk < 9; ++kk) {
                    float pk = s[kk] * inv;
#pragma unroll
                    for (int g = 0; g < 4; ++g) {
                        bf16x8 v = *(const bf16x8*)&Qb2[(w9 + kk) * LQ12 + dh * 32 + g * 8];
#pragma unroll
                        for (int j = 0; j < 8; ++j) o[g * 8 + j] += pk * bf2f(v[j]);
                    }
                }
                const int gr = grow_of(wbase, row);
                if (gr >= 0) {
#pragma unroll
                    for (int q = 0; q < 2; ++q) {
                        u32x4 u;
#pragma unroll
                        for (int e = 0; e < 4; ++e) {
                            int i0 = q * 16 + e * 2 + (e >> 1) * 4;  // not used; replaced below
                            (void)i0;
                        }
#pragma unroll
                        for (int e = 0; e < 4; ++e) {
                            int i0 = q * 16 + e * 4;
                            // pack pairs (i0,i0+1) and (i0+2,i0+3) handled across two u32 slots
                            (void)i0;
                        }
                        // straightforward packing: u[e] covers o[q*16 + e*4 .. +3]? No — u32 holds 2 bf16.
                        // Build explicitly:
#pragma unroll
                        for (int e = 0; e < 4; ++e) {
                            int i0 = q * 8 + e * 2;
                            u[e] = (unsigned)f2b(o[i0]) | ((unsigned)f2b(o[i0 + 1]) << 16);
                        }
                        *(u32x4*)(aout + (size_t)gr * 256 + h * 64 + dh * 32 + q * 8) = u;
                    }
                    // second 16 elements
#pragma unroll
                    for (int q = 2; q < 4; ++q) {
                        u32x4 u;
#pragma unroll
                        for (int e = 0; e < 4; ++e) {
                            int i0 = q * 8 + e * 2;
                            u[e] = (unsigned)f2b(o[i0]) | ((unsigned)f2b(o[i0 + 1]) << 16);
                        }
                        *(u32x4*)(aout + (size_t)gr * 256 + h * 64 + dh * 32 + q * 8) = u;
                    }
                }
            }
        }
        __syncthreads();   // protect Qb vs next head's GEMM writes
    }
}

// ---------------- proj GEMM: [147456][256] bf16 @ Wproj^T -> fp32 out ----------------
// LDS-free: A fragments in registers, W fragments direct from L2, no barriers.
__global__ __launch_bounds__(256) void k_proj(
    const unsigned short* __restrict__ ain,    // bf16 [147456][256]
    const unsigned short* __restrict__ wproj,  // bf16 [256][256] ([N][K])
    float* __restrict__ out)
{
    const int tid = threadIdx.x;
    const int wv = tid >> 6, ln = tid & 63;
    const int lr = ln & 15, lk = ln >> 4;
    const size_t row0 = (size_t)blockIdx.x * 128;

    bf16x8 af[2][8];
#pragma unroll
    for (int mi = 0; mi < 2; ++mi) {
        const size_t row = row0 + wv * 32 + mi * 16 + lr;
#pragma unroll
        for (int kk = 0; kk < 8; ++kk)
            af[mi][kk] = *(const bf16x8*)(ain + row * 256 + kk * 32 + lk * 8);
    }

#pragma unroll
    for (int nc = 0; nc < 4; ++nc) {
        const int j0 = nc * 64;
        f32x4 acc[2][4];
#pragma unroll
        for (int mi = 0; mi < 2; ++mi)
#pragma unroll
            for (int ni = 0; ni < 4; ++ni) {
                f32x4 z = {0.f, 0.f, 0.f, 0.f};
                acc[mi][ni] = z;
            }
#pragma unroll
        for (int kk = 0; kk < 8; ++kk) {
            bf16x8 w[4];
#pragma unroll
            for (int ni = 0; ni < 4; ++ni)
                w[ni] = *(const bf16x8*)(wproj + (size_t)(j0 + ni * 16 + lr) * 256 + kk * 32 + lk * 8);
#pragma unroll
            for (int ni = 0; ni < 4; ++ni) {
                acc[0][ni] = __builtin_amdgcn_mfma_f32_16x16x32_bf16(w[ni], af[0][kk], acc[0][ni], 0, 0, 0);
                acc[1][ni] = __builtin_amdgcn_mfma_f32_16x16x32_bf16(w[ni], af[1][kk], acc[1][ni], 0, 0, 0);
            }
        }
#pragma unroll
        for (int mi = 0; mi < 2; ++mi) {
            const size_t row = row0 + wv * 32 + mi * 16 + lr;
#pragma unroll
            for (int ni = 0; ni < 4; ++ni)
                *(f32x4*)&out[row * 256 + j0 + ni * 16 + lk * 4] = acc[mi][ni];
        }
    }
}

extern "C" void kernel_launch(void* const* d_in, const int* in_sizes, int n_in,
                              void* d_out, int out_size, void* d_ws, size_t ws_size,
                              hipStream_t stream) {
    const float* x  = (const float*)d_in[0];
    const float* wq = (const float*)d_in[1];
    const float* wp = (const float*)d_in[2];
    unsigned short* wsb     = (unsigned short*)d_ws;
    unsigned short* wqkv_b  = wsb;                // 196608 elems
    unsigned short* wproj_b = wsb + 196608;       //  65536 elems
    unsigned short* aout    = wsb + 262144;       // 147456*256 bf16
    float* out = (float*)d_out;

    k_wconv  <<<1024, 256, 0, stream>>>(wq, wp, wsb);
    k_winattn<<<1171, 256, 0, stream>>>(x, wqkv_b, aout);
    k_proj   <<<1152, 256, 0, stream>>>(aout, wproj_b, out);
}

// Round 3
// 385.512 us; speedup vs baseline: 1.3049x; 1.3049x over previous
//
#include <hip/hip_runtime.h>
#include <hip/hip_bf16.h>

using f32x4  = __attribute__((ext_vector_type(4))) float;
using bf16x8 = __attribute__((ext_vector_type(8))) short;
using bf16x4 = __attribute__((ext_vector_type(4))) short;
using u32x2  = __attribute__((ext_vector_type(2))) unsigned int;
using u32x4  = __attribute__((ext_vector_type(4))) unsigned int;

__device__ __forceinline__ float bf2f(short s) {
    unsigned u = ((unsigned)(unsigned short)s) << 16;
    return __builtin_bit_cast(float, u);
}
__device__ __forceinline__ unsigned short f2b(float f) {
    unsigned u = __builtin_bit_cast(unsigned, f);
    unsigned r = u + 0x7FFFu + ((u >> 16) & 1u);   // RNE
    return (unsigned short)(r >> 16);
}

// window-local row -> global x row (7 windows per block, row in [0,63))
__device__ __forceinline__ int grow_of(int wbase, int row) {
    int wi = row / 9;
    int t  = row - wi * 9;
    int w  = wbase + wi;
    if (w >= 16384) return -1;
    int b = w >> 10, rem = w & 1023;
    int wh = rem >> 5, ww = rem & 31;
    int r = t / 3, c = t - r * 3;
    return b * 9216 + (wh * 3 + r) * 96 + ww * 3 + c;
}

// ---------------- weight convert: Wqkv (768x256) + Wproj (256x256) -> bf16 ----------------
__global__ void k_wconv(const float* __restrict__ wq, const float* __restrict__ wp,
                        unsigned short* __restrict__ out) {
    int i = blockIdx.x * 256 + threadIdx.x;       // grid covers exactly 262144
    float v = (i < 196608) ? wq[i] : wp[i - 196608];
    out[i] = f2b(v);
}

// ---------------- fused window-gather + qkv GEMM + attention ----------------
// block: 7 windows (63 rows + 1 pad), 256 threads (4 waves, 2x2 wave-tile grid).
// A in LDS (33.8KB), q/k/v per head in LDS (26.1KB) -> 59.9KB -> 2 blocks/CU.
// W fragments direct from L2, prefetched into 16 regs per part (no spill).
__global__ __launch_bounds__(256) void k_winattn(
    const float* __restrict__ x,
    const unsigned short* __restrict__ wqkv,   // bf16 [768][256]  ([N][K])
    unsigned short* __restrict__ aout)         // bf16 [147456][256], x-row order
{
    constexpr int LDA = 264;                   // elems; 528B row stride (16B aligned)
    constexpr int LQ  = 68;                    // elems; 136B row stride (8B aligned)
    __shared__ unsigned short As[64 * LDA];    // 33792 B
    __shared__ unsigned short Qb[3][64 * LQ];  // 26112 B
    __shared__ int rowmap[64];

    const int tid = threadIdx.x;
    const int wbase = blockIdx.x * 7;
    const int wv = tid >> 6, ln = tid & 63;
    const int lr = ln & 15, lk = ln >> 4;
    const int mw = wv >> 1, nw = wv & 1;       // 2x2 wave tile: rows mw*32+, cols nw*32+

    if (tid < 64)
        rowmap[tid] = (tid < 63) ? grow_of(wbase, tid) : -1;
    __syncthreads();

    // ---- stage x rows -> As (bf16), zeros for pad/invalid rows ----
    for (int idx = tid; idx < 64 * 32; idx += 256) {
        int row = idx >> 5, g = idx & 31;
        int gr = rowmap[row];
        bf16x8 v;
        if (gr >= 0) {
            const f32x4* p = (const f32x4*)(x + (size_t)gr * 256 + g * 8);
            f32x4 f0 = p[0], f1 = p[1];
#pragma unroll
            for (int j = 0; j < 4; ++j) {
                v[j]     = (short)f2b(f0[j]);
                v[4 + j] = (short)f2b(f1[j]);
            }
        } else {
#pragma unroll
            for (int j = 0; j < 8; ++j) v[j] = 0;
        }
        *(bf16x8*)&As[row * LDA + g * 8] = v;
    }
    __syncthreads();

#pragma unroll 1
    for (int h = 0; h < 4; ++h) {
        // ---- qkv GEMM for head h: per part, wave tile M=32 x N=32 ----
#pragma unroll 1
        for (int part = 0; part < 3; ++part) {
            const int j0 = part * 256 + h * 64 + nw * 32;
            // prefetch the wave's W fragments for this part (16 x 16B from L2)
            bf16x8 w[2][8];
#pragma unroll
            for (int ni = 0; ni < 2; ++ni)
#pragma unroll
                for (int kk = 0; kk < 8; ++kk)
                    w[ni][kk] = *(const bf16x8*)(wqkv + (size_t)(j0 + ni * 16 + lr) * 256 + kk * 32 + lk * 8);

            f32x4 acc[2][2];
#pragma unroll
            for (int mi = 0; mi < 2; ++mi)
#pragma unroll
                for (int ni = 0; ni < 2; ++ni) {
                    f32x4 z = {0.f, 0.f, 0.f, 0.f};
                    acc[mi][ni] = z;
                }
#pragma unroll
            for (int kk = 0; kk < 8; ++kk) {
                const int k0 = kk * 32 + lk * 8;
                bf16x8 a0 = *(const bf16x8*)&As[(mw * 32 + lr) * LDA + k0];
                bf16x8 a1 = *(const bf16x8*)&As[(mw * 32 + 16 + lr) * LDA + k0];
                // swapped operands: D[n][m] -> lane holds rows m=lr (A-row), cols n=lk*4+r
                acc[0][0] = __builtin_amdgcn_mfma_f32_16x16x32_bf16(w[0][kk], a0, acc[0][0], 0, 0, 0);
                acc[1][0] = __builtin_amdgcn_mfma_f32_16x16x32_bf16(w[0][kk], a1, acc[1][0], 0, 0, 0);
                acc[0][1] = __builtin_amdgcn_mfma_f32_16x16x32_bf16(w[1][kk], a0, acc[0][1], 0, 0, 0);
                acc[1][1] = __builtin_amdgcn_mfma_f32_16x16x32_bf16(w[1][kk], a1, acc[1][1], 0, 0, 0);
            }
            // write q/k/v tile to LDS: lane holds 4 consecutive cols per (mi,ni)
#pragma unroll
            for (int mi = 0; mi < 2; ++mi)
#pragma unroll
                for (int ni = 0; ni < 2; ++ni) {
                    int row = mw * 32 + mi * 16 + lr;
                    int col = nw * 32 + ni * 16 + lk * 4;
                    u32x2 u;
                    u[0] = (unsigned)f2b(acc[mi][ni][0]) | ((unsigned)f2b(acc[mi][ni][1]) << 16);
                    u[1] = (unsigned)f2b(acc[mi][ni][2]) | ((unsigned)f2b(acc[mi][ni][3]) << 16);
                    *(u32x2*)&Qb[part][row * LQ + col] = u;
                }
        }
        __syncthreads();

        // ---- attention, head h: lane = (row = wv*16 + lr, col-group c = lk) ----
        {
            const int row = wv * 16 + lr;      // 0..63
            const int c   = lk;                // 16 d-cols per lane
            if (row < 63) {
                const int w9 = (row / 9) * 9;
                // q: this lane's 16 cols
                float q[16];
#pragma unroll
                for (int g = 0; g < 4; ++g) {
                    bf16x4 v = *(const bf16x4*)&Qb[0][row * LQ + c * 16 + g * 4];
#pragma unroll
                    for (int j = 0; j < 4; ++j) q[g * 4 + j] = bf2f(v[j]);
                }
                // scores: partial dot over 16 cols, then reduce across the 4 c-groups
                float s[9];
#pragma unroll
                for (int kk = 0; kk < 9; ++kk) {
                    float t = 0.f;
#pragma unroll
                    for (int g = 0; g < 4; ++g) {
                        bf16x4 v = *(const bf16x4*)&Qb[1][(w9 + kk) * LQ + c * 16 + g * 4];
#pragma unroll
                        for (int j = 0; j < 4; ++j) t += q[g * 4 + j] * bf2f(v[j]);
                    }
                    s[kk] = t;
                }
#pragma unroll
                for (int kk = 0; kk < 9; ++kk) {
                    float t = s[kk];
                    t += __shfl_xor(t, 16);
                    t += __shfl_xor(t, 32);
                    s[kk] = t * 0.125f;        // scale = 1/sqrt(64)
                }
                float m = s[0];
#pragma unroll
                for (int kk = 1; kk < 9; ++kk) m = fmaxf(m, s[kk]);
                float sum = 0.f;
#pragma unroll
                for (int kk = 0; kk < 9; ++kk) { s[kk] = __expf(s[kk] - m); sum += s[kk]; }
                float inv = 1.f / sum;
                // PV: this lane's 16 output cols
                float o[16];
#pragma unroll
                for (int d = 0; d < 16; ++d) o[d] = 0.f;
#pragma unroll
                for (int kk = 0; kk < 9; ++kk) {
                    float pk = s[kk] * inv;
#pragma unroll
                    for (int g = 0; g < 4; ++g) {
                        bf16x4 v = *(const bf16x4*)&Qb[2][(w9 + kk) * LQ + c * 16 + g * 4];
#pragma unroll
                        for (int j = 0; j < 4; ++j) o[g * 4 + j] += pk * bf2f(v[j]);
                    }
                }
                const int gr = rowmap[row];
                if (gr >= 0) {
#pragma unroll
                    for (int half = 0; half < 2; ++half) {
                        u32x4 u;
#pragma unroll
                        for (int e = 0; e < 4; ++e) {
                            int i0 = half * 8 + e * 2;
                            u[e] = (unsigned)f2b(o[i0]) | ((unsigned)f2b(o[i0 + 1]) << 16);
                        }
                        *(u32x4*)(aout + (size_t)gr * 256 + h * 64 + c * 16 + half * 8) = u;
                    }
                }
            }
        }
        __syncthreads();   // protect Qb before next head's GEMM writes
    }
}

// ---------------- proj GEMM: [147456][256] bf16 @ Wproj^T -> fp32 out ----------------
// LDS-free: A fragments in registers, W fragments direct from L2, no barriers.
__global__ __launch_bounds__(256) void k_proj(
    const unsigned short* __restrict__ ain,    // bf16 [147456][256]
    const unsigned short* __restrict__ wproj,  // bf16 [256][256] ([N][K])
    float* __restrict__ out)
{
    const int tid = threadIdx.x;
    const int wv = tid >> 6, ln = tid & 63;
    const int lr = ln & 15, lk = ln >> 4;
    const size_t row0 = (size_t)blockIdx.x * 128;

    bf16x8 af[2][8];
#pragma unroll
    for (int mi = 0; mi < 2; ++mi) {
        const size_t row = row0 + wv * 32 + mi * 16 + lr;
#pragma unroll
        for (int kk = 0; kk < 8; ++kk)
            af[mi][kk] = *(const bf16x8*)(ain + row * 256 + kk * 32 + lk * 8);
    }

#pragma unroll
    for (int nc = 0; nc < 4; ++nc) {
        const int j0 = nc * 64;
        f32x4 acc[2][4];
#pragma unroll
        for (int mi = 0; mi < 2; ++mi)
#pragma unroll
            for (int ni = 0; ni < 4; ++ni) {
                f32x4 z = {0.f, 0.f, 0.f, 0.f};
                acc[mi][ni] = z;
            }
#pragma unroll
        for (int kk = 0; kk < 8; ++kk) {
            bf16x8 w[4];
#pragma unroll
            for (int ni = 0; ni < 4; ++ni)
                w[ni] = *(const bf16x8*)(wproj + (size_t)(j0 + ni * 16 + lr) * 256 + kk * 32 + lk * 8);
#pragma unroll
            for (int ni = 0; ni < 4; ++ni) {
                acc[0][ni] = __builtin_amdgcn_mfma_f32_16x16x32_bf16(w[ni], af[0][kk], acc[0][ni], 0, 0, 0);
                acc[1][ni] = __builtin_amdgcn_mfma_f32_16x16x32_bf16(w[ni], af[1][kk], acc[1][ni], 0, 0, 0);
            }
        }
#pragma unroll
        for (int mi = 0; mi < 2; ++mi) {
            const size_t row = row0 + wv * 32 + mi * 16 + lr;
#pragma unroll
            for (int ni = 0; ni < 4; ++ni)
                *(f32x4*)&out[row * 256 + j0 + ni * 16 + lk * 4] = acc[mi][ni];
        }
    }
}

extern "C" void kernel_launch(void* const* d_in, const int* in_sizes, int n_in,
                              void* d_out, int out_size, void* d_ws, size_t ws_size,
                              hipStream_t stream) {
    const float* x  = (const float*)d_in[0];
    const float* wq = (const float*)d_in[1];
    const float* wp = (const float*)d_in[2];
    unsigned short* wsb     = (unsigned short*)d_ws;
    unsigned short* wqkv_b  = wsb;                // 196608 elems
    unsigned short* wproj_b = wsb + 196608;       //  65536 elems
    unsigned short* aout    = wsb + 262144;       // 147456*256 bf16
    float* out = (float*)d_out;

    k_wconv  <<<1024, 256, 0, stream>>>(wq, wp, wsb);
    k_winattn<<<2341, 256, 0, stream>>>(x, wqkv_b, aout);
    k_proj   <<<1152, 256, 0, stream>>>(aout, wproj_b, out);
}

// Round 4
// 319.798 us; speedup vs baseline: 1.5730x; 1.2055x over previous
//
#include <hip/hip_runtime.h>
#include <hip/hip_bf16.h>

using f32x4  = __attribute__((ext_vector_type(4))) float;
using bf16x8 = __attribute__((ext_vector_type(8))) short;
using bf16x4 = __attribute__((ext_vector_type(4))) short;
using u32x2  = __attribute__((ext_vector_type(2))) unsigned int;
using u32x4  = __attribute__((ext_vector_type(4))) unsigned int;

__device__ __forceinline__ float bf2f(short s) {
    unsigned u = ((unsigned)(unsigned short)s) << 16;
    return __builtin_bit_cast(float, u);
}
__device__ __forceinline__ unsigned short f2b(float f) {
    unsigned u = __builtin_bit_cast(unsigned, f);
    unsigned r = u + 0x7FFFu + ((u >> 16) & 1u);   // RNE
    return (unsigned short)(r >> 16);
}

// window-order row r (0..147455) -> x row
__device__ __forceinline__ int xrow_of(int r) {
    int w = r / 9, t = r - w * 9;
    int b = w >> 10, rem = w & 1023;
    int wh = rem >> 5, ww = rem & 31;
    int rr = t / 3, cc = t - rr * 3;
    return b * 9216 + (wh * 3 + rr) * 96 + ww * 3 + cc;
}

// ---------------- weight convert: Wqkv (768x256) + Wproj (256x256) -> bf16 ----------------
__global__ void k_wconv(const float* __restrict__ wq, const float* __restrict__ wp,
                        unsigned short* __restrict__ out) {
    int i = blockIdx.x * 256 + threadIdx.x;       // grid covers exactly 262144
    float v = (i < 196608) ? wq[i] : wp[i - 196608];
    out[i] = f2b(v);
}

// ==================== PRIMARY PATH (3-kernel split) ====================

// ---- k_qkv: gathered GEMM, M=147456 (window order), N=768, K=256 ----
// A in registers per wave; W chunk staged in XOR-swizzled LDS (32 KB).
__global__ __launch_bounds__(256) void k_qkv(
    const float* __restrict__ x,
    const unsigned short* __restrict__ wqkv,   // bf16 [768][256]
    unsigned short* __restrict__ qkv)          // bf16 [147456][768], window order
{
    __shared__ unsigned short Wt[64 * 256];    // 32 KB, 16B-chunk swizzled
    const int tid = threadIdx.x;
    const int wv = tid >> 6, ln = tid & 63;
    const int lr = ln & 15, lk = ln >> 4;
    const int row0 = blockIdx.x * 128;

    // gather A rows (fp32 -> bf16) into registers
    bf16x8 af[2][8];
    int rrow[2];
#pragma unroll
    for (int mi = 0; mi < 2; ++mi) {
        int r = row0 + wv * 32 + mi * 16 + lr;
        rrow[mi] = r;
        const float* xp = x + (size_t)xrow_of(r) * 256;
#pragma unroll
        for (int kk = 0; kk < 8; ++kk) {
            const f32x4* p = (const f32x4*)(xp + kk * 32 + lk * 8);
            f32x4 f0 = p[0], f1 = p[1];
            bf16x8 v;
#pragma unroll
            for (int j = 0; j < 4; ++j) {
                v[j]     = (short)f2b(f0[j]);
                v[4 + j] = (short)f2b(f1[j]);
            }
            af[mi][kk] = v;
        }
    }

#pragma unroll 1
    for (int nc = 0; nc < 12; ++nc) {
        const int j0 = nc * 64;
        __syncthreads();                        // Wt free
        for (int idx = tid; idx < 2048; idx += 256) {
            int row = idx >> 5, ch = idx & 31;
            int dch = ch ^ ((row & 7) << 2);    // 16B-granule XOR swizzle
            *(bf16x8*)&Wt[row * 256 + dch * 8] =
                *(const bf16x8*)(wqkv + (size_t)(j0 + row) * 256 + ch * 8);
        }
        __syncthreads();

        f32x4 acc[2][4];
#pragma unroll
        for (int mi = 0; mi < 2; ++mi)
#pragma unroll
            for (int ni = 0; ni < 4; ++ni) {
                f32x4 z = {0.f, 0.f, 0.f, 0.f};
                acc[mi][ni] = z;
            }
#pragma unroll
        for (int kk = 0; kk < 8; ++kk) {
            bf16x8 w[4];
#pragma unroll
            for (int ni = 0; ni < 4; ++ni) {
                int wrow = ni * 16 + lr;
                int ch = (kk * 4 + lk) ^ ((wrow & 7) << 2);
                w[ni] = *(const bf16x8*)&Wt[wrow * 256 + ch * 8];
            }
#pragma unroll
            for (int ni = 0; ni < 4; ++ni) {
                acc[0][ni] = __builtin_amdgcn_mfma_f32_16x16x32_bf16(w[ni], af[0][kk], acc[0][ni], 0, 0, 0);
                acc[1][ni] = __builtin_amdgcn_mfma_f32_16x16x32_bf16(w[ni], af[1][kk], acc[1][ni], 0, 0, 0);
            }
        }
        // lane holds C[row=af-row][col=j0+ni*16+lk*4+r]
#pragma unroll
        for (int mi = 0; mi < 2; ++mi)
#pragma unroll
            for (int ni = 0; ni < 4; ++ni) {
                u32x2 u;
                u[0] = (unsigned)f2b(acc[mi][ni][0]) | ((unsigned)f2b(acc[mi][ni][1]) << 16);
                u[1] = (unsigned)f2b(acc[mi][ni][2]) | ((unsigned)f2b(acc[mi][ni][3]) << 16);
                *(u32x2*)(qkv + (size_t)rrow[mi] * 768 + j0 + ni * 16 + lk * 4) = u;
            }
    }
}

// ---- k_attn: one block per (7-window group, head); K,V staged in LDS ----
// reads q/k/v from qkv; writes attn-out IN PLACE into the q region.
__global__ __launch_bounds__(256) void k_attn(
    unsigned short* __restrict__ qkv)          // bf16 [147456][768]
{
    constexpr int LQ = 68;
    __shared__ unsigned short KV[2][64 * LQ];  // 17.4 KB
    const int tid = threadIdx.x;
    const int h  = blockIdx.y;
    const int r0 = blockIdx.x * 63;

    for (int idx = tid; idx < 1024; idx += 256) {
        int kv  = idx >> 9;
        int row = (idx >> 3) & 63;
        int ch  = idx & 7;
        int r = r0 + row;
        bf16x8 v;
        if (row < 63 && r < 147456) {
            v = *(const bf16x8*)(qkv + (size_t)r * 768 + 256 + (kv << 8) + h * 64 + ch * 8);
        } else {
#pragma unroll
            for (int j = 0; j < 8; ++j) v[j] = 0;
        }
        *(bf16x8*)&KV[kv][row * LQ + ch * 8] = v;
    }
    __syncthreads();

    const int row = tid >> 2, c = tid & 3;     // lane = (window row, 16-col group)
    const int r = r0 + row;
    if (row < 63 && r < 147456) {
        const int w9 = (row / 9) * 9;
        float q[16];
#pragma unroll
        for (int g = 0; g < 2; ++g) {
            bf16x8 v = *(const bf16x8*)(qkv + (size_t)r * 768 + h * 64 + c * 16 + g * 8);
#pragma unroll
            for (int j = 0; j < 8; ++j) q[g * 8 + j] = bf2f(v[j]);
        }
        float s[9];
#pragma unroll
        for (int kk = 0; kk < 9; ++kk) {
            float t = 0.f;
#pragma unroll
            for (int g = 0; g < 2; ++g) {
                bf16x8 v = *(const bf16x8*)&KV[0][(w9 + kk) * LQ + c * 16 + g * 8];
#pragma unroll
                for (int j = 0; j < 8; ++j) t += q[g * 8 + j] * bf2f(v[j]);
            }
            s[kk] = t;
        }
#pragma unroll
        for (int kk = 0; kk < 9; ++kk) {
            float t = s[kk];
            t += __shfl_xor(t, 1);
            t += __shfl_xor(t, 2);
            s[kk] = t * 0.125f;                // 1/sqrt(64)
        }
        float m = s[0];
#pragma unroll
        for (int kk = 1; kk < 9; ++kk) m = fmaxf(m, s[kk]);
        float sum = 0.f;
#pragma unroll
        for (int kk = 0; kk < 9; ++kk) { s[kk] = __expf(s[kk] - m); sum += s[kk]; }
        float inv = 1.f / sum;
        float o[16];
#pragma unroll
        for (int d = 0; d < 16; ++d) o[d] = 0.f;
#pragma unroll
        for (int kk = 0; kk < 9; ++kk) {
            float pk = s[kk] * inv;
#pragma unroll
            for (int g = 0; g < 2; ++g) {
                bf16x8 v = *(const bf16x8*)&KV[1][(w9 + kk) * LQ + c * 16 + g * 8];
#pragma unroll
                for (int j = 0; j < 8; ++j) o[g * 8 + j] += pk * bf2f(v[j]);
            }
        }
        // overwrite this lane's own q slice with attn-out
#pragma unroll
        for (int half = 0; half < 2; ++half) {
            u32x4 u;
#pragma unroll
            for (int e = 0; e < 4; ++e) {
                int i0 = half * 8 + e * 2;
                u[e] = (unsigned)f2b(o[i0]) | ((unsigned)f2b(o[i0 + 1]) << 16);
            }
            *(u32x4*)(qkv + (size_t)r * 768 + h * 64 + c * 16 + half * 8) = u;
        }
    }
}

// ---- k_proj2: window-order attn-out (q region of qkv) @ Wproj^T -> fp32 out (x-order scatter) ----
__global__ __launch_bounds__(256) void k_proj2(
    const unsigned short* __restrict__ qkv,    // attn-out at cols 0..255, stride 768
    const unsigned short* __restrict__ wproj,  // bf16 [256][256]
    float* __restrict__ out)
{
    const int tid = threadIdx.x;
    const int wv = tid >> 6, ln = tid & 63;
    const int lr = ln & 15, lk = ln >> 4;
    const int row0 = blockIdx.x * 128;

    bf16x8 af[2][8];
    int xr[2];
#pragma unroll
    for (int mi = 0; mi < 2; ++mi) {
        int r = row0 + wv * 32 + mi * 16 + lr;
        xr[mi] = xrow_of(r);
#pragma unroll
        for (int kk = 0; kk < 8; ++kk)
            af[mi][kk] = *(const bf16x8*)(qkv + (size_t)r * 768 + kk * 32 + lk * 8);
    }

#pragma unroll
    for (int nc = 0; nc < 4; ++nc) {
        const int j0 = nc * 64;
        f32x4 acc[2][4];
#pragma unroll
        for (int mi = 0; mi < 2; ++mi)
#pragma unroll
            for (int ni = 0; ni < 4; ++ni) {
                f32x4 z = {0.f, 0.f, 0.f, 0.f};
                acc[mi][ni] = z;
            }
#pragma unroll
        for (int kk = 0; kk < 8; ++kk) {
            bf16x8 w[4];
#pragma unroll
            for (int ni = 0; ni < 4; ++ni)
                w[ni] = *(const bf16x8*)(wproj + (size_t)(j0 + ni * 16 + lr) * 256 + kk * 32 + lk * 8);
#pragma unroll
            for (int ni = 0; ni < 4; ++ni) {
                acc[0][ni] = __builtin_amdgcn_mfma_f32_16x16x32_bf16(w[ni], af[0][kk], acc[0][ni], 0, 0, 0);
                acc[1][ni] = __builtin_amdgcn_mfma_f32_16x16x32_bf16(w[ni], af[1][kk], acc[1][ni], 0, 0, 0);
            }
        }
#pragma unroll
        for (int mi = 0; mi < 2; ++mi)
#pragma unroll
            for (int ni = 0; ni < 4; ++ni)
                *(f32x4*)&out[(size_t)xr[mi] * 256 + j0 + ni * 16 + lk * 4] = acc[mi][ni];
    }
}

// ==================== FALLBACK PATH (round-3 kernels, ~76 MB ws) ====================

__device__ __forceinline__ int grow_of(int wbase, int row) {
    int wi = row / 9;
    int t  = row - wi * 9;
    int w  = wbase + wi;
    if (w >= 16384) return -1;
    int b = w >> 10, rem = w & 1023;
    int wh = rem >> 5, ww = rem & 31;
    int r = t / 3, c = t - r * 3;
    return b * 9216 + (wh * 3 + r) * 96 + ww * 3 + c;
}

__global__ __launch_bounds__(256) void k_winattn_fb(
    const float* __restrict__ x,
    const unsigned short* __restrict__ wqkv,
    unsigned short* __restrict__ aout)
{
    constexpr int LDA = 264;
    constexpr int LQ  = 68;
    __shared__ unsigned short As[64 * LDA];
    __shared__ unsigned short Qb[3][64 * LQ];
    __shared__ int rowmap[64];

    const int tid = threadIdx.x;
    const int wbase = blockIdx.x * 7;
    const int wv = tid >> 6, ln = tid & 63;
    const int lr = ln & 15, lk = ln >> 4;
    const int mw = wv >> 1, nw = wv & 1;

    if (tid < 64)
        rowmap[tid] = (tid < 63) ? grow_of(wbase, tid) : -1;
    __syncthreads();

    for (int idx = tid; idx < 64 * 32; idx += 256) {
        int row = idx >> 5, g = idx & 31;
        int gr = rowmap[row];
        bf16x8 v;
        if (gr >= 0) {
            const f32x4* p = (const f32x4*)(x + (size_t)gr * 256 + g * 8);
            f32x4 f0 = p[0], f1 = p[1];
#pragma unroll
            for (int j = 0; j < 4; ++j) {
                v[j]     = (short)f2b(f0[j]);
                v[4 + j] = (short)f2b(f1[j]);
            }
        } else {
#pragma unroll
            for (int j = 0; j < 8; ++j) v[j] = 0;
        }
        *(bf16x8*)&As[row * LDA + g * 8] = v;
    }
    __syncthreads();

#pragma unroll 1
    for (int h = 0; h < 4; ++h) {
#pragma unroll 1
        for (int part = 0; part < 3; ++part) {
            const int j0 = part * 256 + h * 64 + nw * 32;
            bf16x8 w[2][8];
#pragma unroll
            for (int ni = 0; ni < 2; ++ni)
#pragma unroll
                for (int kk = 0; kk < 8; ++kk)
                    w[ni][kk] = *(const bf16x8*)(wqkv + (size_t)(j0 + ni * 16 + lr) * 256 + kk * 32 + lk * 8);

            f32x4 acc[2][2];
#pragma unroll
            for (int mi = 0; mi < 2; ++mi)
#pragma unroll
                for (int ni = 0; ni < 2; ++ni) {
                    f32x4 z = {0.f, 0.f, 0.f, 0.f};
                    acc[mi][ni] = z;
                }
#pragma unroll
            for (int kk = 0; kk < 8; ++kk) {
                const int k0 = kk * 32 + lk * 8;
                bf16x8 a0 = *(const bf16x8*)&As[(mw * 32 + lr) * LDA + k0];
                bf16x8 a1 = *(const bf16x8*)&As[(mw * 32 + 16 + lr) * LDA + k0];
                acc[0][0] = __builtin_amdgcn_mfma_f32_16x16x32_bf16(w[0][kk], a0, acc[0][0], 0, 0, 0);
                acc[1][0] = __builtin_amdgcn_mfma_f32_16x16x32_bf16(w[0][kk], a1, acc[1][0], 0, 0, 0);
                acc[0][1] = __builtin_amdgcn_mfma_f32_16x16x32_bf16(w[1][kk], a0, acc[0][1], 0, 0, 0);
                acc[1][1] = __builtin_amdgcn_mfma_f32_16x16x32_bf16(w[1][kk], a1, acc[1][1], 0, 0, 0);
            }
#pragma unroll
            for (int mi = 0; mi < 2; ++mi)
#pragma unroll
                for (int ni = 0; ni < 2; ++ni) {
                    int row = mw * 32 + mi * 16 + lr;
                    int col = nw * 32 + ni * 16 + lk * 4;
                    u32x2 u;
                    u[0] = (unsigned)f2b(acc[mi][ni][0]) | ((unsigned)f2b(acc[mi][ni][1]) << 16);
                    u[1] = (unsigned)f2b(acc[mi][ni][2]) | ((unsigned)f2b(acc[mi][ni][3]) << 16);
                    *(u32x2*)&Qb[part][row * LQ + col] = u;
                }
        }
        __syncthreads();
        {
            const int row = wv * 16 + lr;
            const int c   = lk;
            if (row < 63) {
                const int w9 = (row / 9) * 9;
                float q[16];
#pragma unroll
                for (int g = 0; g < 4; ++g) {
                    bf16x4 v = *(const bf16x4*)&Qb[0][row * LQ + c * 16 + g * 4];
#pragma unroll
                    for (int j = 0; j < 4; ++j) q[g * 4 + j] = bf2f(v[j]);
                }
                float s[9];
#pragma unroll
                for (int kk = 0; kk < 9; ++kk) {
                    float t = 0.f;
#pragma unroll
                    for (int g = 0; g < 4; ++g) {
                        bf16x4 v = *(const bf16x4*)&Qb[1][(w9 + kk) * LQ + c * 16 + g * 4];
#pragma unroll
                        for (int j = 0; j < 4; ++j) t += q[g * 4 + j] * bf2f(v[j]);
                    }
                    s[kk] = t;
                }
#pragma unroll
                for (int kk = 0; kk < 9; ++kk) {
                    float t = s[kk];
                    t += __shfl_xor(t, 16);
                    t += __shfl_xor(t, 32);
                    s[kk] = t * 0.125f;
                }
                float m = s[0];
#pragma unroll
                for (int kk = 1; kk < 9; ++kk) m = fmaxf(m, s[kk]);
                float sum = 0.f;
#pragma unroll
                for (int kk = 0; kk < 9; ++kk) { s[kk] = __expf(s[kk] - m); sum += s[kk]; }
                float inv = 1.f / sum;
                float o[16];
#pragma unroll
                for (int d = 0; d < 16; ++d) o[d] = 0.f;
#pragma unroll
                for (int kk = 0; kk < 9; ++kk) {
                    float pk = s[kk] * inv;
#pragma unroll
                    for (int g = 0; g < 4; ++g) {
                        bf16x4 v = *(const bf16x4*)&Qb[2][(w9 + kk) * LQ + c * 16 + g * 4];
#pragma unroll
                        for (int j = 0; j < 4; ++j) o[g * 4 + j] += pk * bf2f(v[j]);
                    }
                }
                const int gr = rowmap[row];
                if (gr >= 0) {
#pragma unroll
                    for (int half = 0; half < 2; ++half) {
                        u32x4 u;
#pragma unroll
                        for (int e = 0; e < 4; ++e) {
                            int i0 = half * 8 + e * 2;
                            u[e] = (unsigned)f2b(o[i0]) | ((unsigned)f2b(o[i0 + 1]) << 16);
                        }
                        *(u32x4*)(aout + (size_t)gr * 256 + h * 64 + c * 16 + half * 8) = u;
                    }
                }
            }
        }
        __syncthreads();
    }
}

__global__ __launch_bounds__(256) void k_proj_fb(
    const unsigned short* __restrict__ ain,
    const unsigned short* __restrict__ wproj,
    float* __restrict__ out)
{
    const int tid = threadIdx.x;
    const int wv = tid >> 6, ln = tid & 63;
    const int lr = ln & 15, lk = ln >> 4;
    const size_t row0 = (size_t)blockIdx.x * 128;

    bf16x8 af[2][8];
#pragma unroll
    for (int mi = 0; mi < 2; ++mi) {
        const size_t row = row0 + wv * 32 + mi * 16 + lr;
#pragma unroll
        for (int kk = 0; kk < 8; ++kk)
            af[mi][kk] = *(const bf16x8*)(ain + row * 256 + kk * 32 + lk * 8);
    }
#pragma unroll
    for (int nc = 0; nc < 4; ++nc) {
        const int j0 = nc * 64;
        f32x4 acc[2][4];
#pragma unroll
        for (int mi = 0; mi < 2; ++mi)
#pragma unroll
            for (int ni = 0; ni < 4; ++ni) {
                f32x4 z = {0.f, 0.f, 0.f, 0.f};
                acc[mi][ni] = z;
            }
#pragma unroll
        for (int kk = 0; kk < 8; ++kk) {
            bf16x8 w[4];
#pragma unroll
            for (int ni = 0; ni < 4; ++ni)
                w[ni] = *(const bf16x8*)(wproj + (size_t)(j0 + ni * 16 + lr) * 256 + kk * 32 + lk * 8);
#pragma unroll
            for (int ni = 0; ni < 4; ++ni) {
                acc[0][ni] = __builtin_amdgcn_mfma_f32_16x16x32_bf16(w[ni], af[0][kk], acc[0][ni], 0, 0, 0);
                acc[1][ni] = __builtin_amdgcn_mfma_f32_16x16x32_bf16(w[ni], af[1][kk], acc[1][ni], 0, 0, 0);
            }
        }
#pragma unroll
        for (int mi = 0; mi < 2; ++mi) {
            const size_t row = row0 + wv * 32 + mi * 16 + lr;
#pragma unroll
            for (int ni = 0; ni < 4; ++ni)
                *(f32x4*)&out[row * 256 + j0 + ni * 16 + lk * 4] = acc[mi][ni];
        }
    }
}

extern "C" void kernel_launch(void* const* d_in, const int* in_sizes, int n_in,
                              void* d_out, int out_size, void* d_ws, size_t ws_size,
                              hipStream_t stream) {
    const float* x  = (const float*)d_in[0];
    const float* wq = (const float*)d_in[1];
    const float* wp = (const float*)d_in[2];
    unsigned short* wsb     = (unsigned short*)d_ws;
    unsigned short* wqkv_b  = wsb;                // 196608 elems
    unsigned short* wproj_b = wsb + 196608;       //  65536 elems
    float* out = (float*)d_out;

    k_wconv<<<1024, 256, 0, stream>>>(wq, wp, wsb);

    const size_t need = 524288ULL + 147456ULL * 768ULL * 2ULL;   // weights + qkv
    if (ws_size >= need) {
        unsigned short* qkv = wsb + 262144;       // bf16 [147456][768]
        k_qkv  <<<1152, 256, 0, stream>>>(x, wqkv_b, qkv);
        k_attn <<<dim3(2341, 4), 256, 0, stream>>>(qkv);
        k_proj2<<<1152, 256, 0, stream>>>(qkv, wproj_b, out);
    } else {
        unsigned short* aout = wsb + 262144;      // bf16 [147456][256], x order
        k_winattn_fb<<<2341, 256, 0, stream>>>(x, wqkv_b, aout);
        k_proj_fb  <<<1152, 256, 0, stream>>>(aout, wproj_b, out);
    }
}